// Round 3
// baseline (1045.985 us; speedup 1.0000x reference)
//
#include <hip/hip_runtime.h>
#include <hip/hip_bf16.h>
#include <math.h>

#define S_DIM 16
#define O_DIM 8
#define J_DIM 32
#define B_DIM 4096
#define HID 240
#define OHID 512

typedef __attribute__((ext_vector_type(8))) short bf16x8;
typedef __attribute__((ext_vector_type(4))) float f32x4;
#define MFMA16(a,b,c) __builtin_amdgcn_mfma_f32_16x16x32_bf16((a),(b),(c),0,0,0)

// ws layout (float offsets)
#define WS_XPRED   0                                  // [B,16]
#define WS_INNO    (WS_XPRED + B_DIM*S_DIM)           // [B,8]
#define WS_XIN0    (WS_INNO + B_DIM*O_DIM)            // [B,240]
#define WS_GH      (WS_XIN0 + B_DIM*HID)              // [960]
#define WS_WB_OFF  ((WS_GH + 960) * 4)                // byte offset: bf16 weights

// out layout (float offsets)
#define OUT_X      0
#define OUT_P      (B_DIM*S_DIM)                      // 65536
#define OUT_REG    (2*B_DIM*S_DIM)                    // 131072
#define OUT_ENS    (2*B_DIM*S_DIM + 1)                // 131073

// fast RNE float->bf16 (inputs finite)
__device__ __forceinline__ unsigned short cvt_bf16(float f) {
    unsigned u = __builtin_bit_cast(unsigned, f);
    u += 0x7FFFu + ((u >> 16) & 1u);
    return (unsigned short)(u >> 16);
}
__device__ __forceinline__ float fast_sigmoid(float x) {
    // 1/(1+2^(-x*log2e))
    float e = __builtin_amdgcn_exp2f(-1.4426950408889634f * x);
    return __builtin_amdgcn_rcpf(1.0f + e);
}
__device__ __forceinline__ float fast_tanh(float x) {
    // 1 - 2/(e^{2x}+1); saturates correctly at +-inf
    float e = __builtin_amdgcn_exp2f(2.8853900817779268f * x);
    return 1.0f - 2.0f * __builtin_amdgcn_rcpf(e + 1.0f);
}

// ---------------------------------------------------------------------------
// aux: cast weights to bf16 (K-padded) + GRU gh precompute
// ---------------------------------------------------------------------------
__global__ void k_aux(const float* __restrict__ W_ih, const float* __restrict__ W_hh,
                      const float* __restrict__ b_ih, const float* __restrict__ b_hh,
                      const float* __restrict__ h_init,
                      const float* __restrict__ W_o1, const float* __restrict__ W_o2,
                      unsigned short* __restrict__ Wihb, unsigned short* __restrict__ Wo1b,
                      unsigned short* __restrict__ Wo2b, float* __restrict__ ghb)
{
    int t = blockIdx.x * 256 + threadIdx.x;
    if (t < 768*256) {
        int n = t >> 8, k = t & 255;
        float v = (n < 720 && k < 240) ? W_ih[n*240 + k] : 0.0f;
        Wihb[t] = cvt_bf16(v);
    } else if (t < 768*256 + 512*256) {
        int u = t - 768*256;
        int n = u >> 8, k = u & 255;
        float v = (k < 240) ? W_o1[n*240 + k] : 0.0f;
        Wo1b[u] = cvt_bf16(v);
    } else if (t < 768*256 + 512*256 + 128*512) {
        int u = t - 768*256 - 512*256;
        Wo2b[u] = cvt_bf16(W_o2[u]);
    }
    if (t < 720) {
        float a = b_hh[t];
        const float* wr = W_hh + t*240;
        for (int k = 0; k < 240; k++) a = fmaf(h_init[k], wr[k], a);
        if (t < 480) {
            ghb[t] = b_ih[t] + a;            // r/z gates: bias fully folded
        } else {
            ghb[t] = b_ih[t];                // n gate: additive part
            ghb[t + 240] = a;                // n gate: part multiplied by r
        }
    }
}

// ---------------------------------------------------------------------------
// pre (fused pre_a+pre_b): Kalman prefix + x_in0 = relu(feats@W_fc^T+b)
// grid (16,16): x = b-chunk of 256, y = h-chunk of 15. feats in registers;
// W_fc streamed via wave-uniform scalar loads.
// ---------------------------------------------------------------------------
__global__ void k_pre(const float* __restrict__ y, const float* __restrict__ xprev,
                      const float* __restrict__ F, const float* __restrict__ Hm,
                      const float* __restrict__ Wfc, const float* __restrict__ bfc,
                      float* __restrict__ x_pred, float* __restrict__ inno,
                      float* __restrict__ x_in0)
{
    __shared__ float sF[256], sH[128];
    int tid = threadIdx.x;
    sF[tid] = F[tid];
    if (tid < 128) sH[tid] = Hm[tid];
    __syncthreads();
    int b = blockIdx.x * 256 + tid;
    float xf[16], xp[16], ft[48];
    #pragma unroll
    for (int s = 0; s < 16; s++) xf[s] = xprev[b*16 + s];
    #pragma unroll
    for (int s = 0; s < 16; s++) {
        float a = 0.f;
        #pragma unroll
        for (int k = 0; k < 16; k++) a = fmaf(xf[k], sF[s*16 + k], a);
        xp[s] = a;
    }
    #pragma unroll
    for (int o = 0; o < 8; o++) {
        float a = 0.f;
        #pragma unroll
        for (int k = 0; k < 16; k++) a = fmaf(xp[k], sH[o*16 + k], a);
        float inn = y[b*8 + o] - a;
        ft[16 + o] = inn;
        ft[40 + o] = inn;
    }
    #pragma unroll
    for (int s = 0; s < 16; s++) { ft[s] = xf[s] - xp[s]; ft[24 + s] = 0.f; }
    if (blockIdx.y == 0) {
        #pragma unroll
        for (int s = 0; s < 16; s++) x_pred[b*16 + s] = xp[s];
        #pragma unroll
        for (int o = 0; o < 8; o++) inno[b*8 + o] = ft[16 + o];
    }
    const int h0 = blockIdx.y * 15;
    for (int h = h0; h < h0 + 15; h++) {
        float a = bfc[h];
        const float* wr = Wfc + h*48;          // wave-uniform -> s_load broadcast
        #pragma unroll
        for (int k = 0; k < 48; k++) a = fmaf(ft[k], wr[k], a);
        x_in0[(size_t)b*240 + h] = fmaxf(a, 0.f);
    }
}

// ---------------------------------------------------------------------------
// main: bf16 MFMA fused chain. 32 (j,b)-rows/block, 4 waves, LDS 52KB -> 3/CU.
// All u1/u2 HBM reads issued in phase 0 (float4 / packed 64-bit mask).
// ---------------------------------------------------------------------------
#define XS_STRIDE 264
#define O1_STRIDE 520

__global__ __launch_bounds__(256, 3) void k_main(
    const float* __restrict__ x_in0, const float* __restrict__ u1,
    const float* __restrict__ u2,
    const unsigned short* __restrict__ Wihb, const float* __restrict__ ghb,
    const float* __restrict__ h_init,
    const unsigned short* __restrict__ Wo1b, const float* __restrict__ b_out1,
    const unsigned short* __restrict__ Wo2b, const float* __restrict__ b_out2,
    const float* __restrict__ x_pred, const float* __restrict__ inno,
    float* __restrict__ ens)
{
    __shared__ __align__(16) char smem[53248];
    unsigned short* O1s = (unsigned short*)smem;            // [32][520], overlays Xs
    unsigned short* Xs  = (unsigned short*)smem;            // [32][264]
    unsigned short* Hs  = (unsigned short*)(smem + 33280);  // [32][264]
    float* XPs   = (float*)(smem + 50176);                  // [32][16]
    float* InnoS = (float*)(smem + 52224);                  // [32][8]

    const int tid = threadIdx.x;
    const int j  = blockIdx.x >> 7;
    const int b0 = (blockIdx.x & 127) << 5;
    const int wave = tid >> 6;
    const int l15  = tid & 15;
    const int quad = (tid >> 4) & 3;

    // ---- phase 0a: u2 -> per-lane 64-bit dropout mask (one burst, nontemporal) ----
    unsigned long long m2 = 0;
    {
        const float* u2b = u2 + ((size_t)(j*B_DIM + b0) << 9);
        #pragma unroll
        for (int it = 0; it < 8; it++) {
            const int n = (wave*8 + it)*16 + l15;
            #pragma unroll
            for (int m = 0; m < 2; m++)
                #pragma unroll
                for (int r = 0; r < 4; r++) {
                    const int row = (m << 4) + (quad << 2) + r;
                    float uu = __builtin_nontemporal_load(&u2b[((size_t)row << 9) + n]);
                    if (uu > 0.65f) m2 |= (1ull << (it*8 + m*4 + r));
                }
        }
    }

    // ---- phase 0b: masked bf16 X tile via float4 ----
    {
        const f32x4* u1b = (const f32x4*)(u1 + (size_t)(j*B_DIM + b0) * 240);
        const f32x4* xb  = (const f32x4*)(x_in0 + (size_t)b0 * 240);
        #pragma unroll
        for (int q = 0; q < 8; q++) {
            int f = q*256 + tid;
            if (f < 1920) {
                int row = f / 60, c4 = f - row*60;
                f32x4 uv = __builtin_nontemporal_load(&u1b[f]);
                f32x4 xv = xb[f];
                ushort4 o;
                o.x = (uv.x > 0.5f) ? cvt_bf16(2.0f*xv.x) : (unsigned short)0;
                o.y = (uv.y > 0.5f) ? cvt_bf16(2.0f*xv.y) : (unsigned short)0;
                o.z = (uv.z > 0.5f) ? cvt_bf16(2.0f*xv.z) : (unsigned short)0;
                o.w = (uv.w > 0.5f) ? cvt_bf16(2.0f*xv.w) : (unsigned short)0;
                *(ushort4*)&Xs[row*XS_STRIDE + (c4 << 2)] = o;
            }
        }
    }
    // zero pad cols 240..255 of Xs and Hs
    for (int p = tid; p < 512; p += 256) {
        int row = p >> 4, c = 240 + (p & 15);
        Xs[row*XS_STRIDE + c] = 0;
        Hs[row*XS_STRIDE + c] = 0;
    }
    XPs[tid]       = x_pred[(size_t)b0*16 + tid];
    XPs[tid + 256] = x_pred[(size_t)b0*16 + 256 + tid];
    InnoS[tid]     = inno[(size_t)b0*8 + tid];
    __syncthreads();

    const f32x4 zero4 = {0.f, 0.f, 0.f, 0.f};

    // ---- GEMM1: gx = X @ W_ih^T (3 gates x 15 n-tiles; tile 15 = padding) ----
    {
        f32x4 accR[4][2], accZ[4][2], accN[4][2];
        #pragma unroll
        for (int it = 0; it < 4; it++)
            #pragma unroll
            for (int m = 0; m < 2; m++) { accR[it][m] = zero4; accZ[it][m] = zero4; accN[it][m] = zero4; }

        #pragma unroll
        for (int ks = 0; ks < 8; ks++) {
            const int ko = ks*32 + quad*8;
            bf16x8 a0 = *(const bf16x8*)&Xs[l15*XS_STRIDE + ko];
            bf16x8 a1 = *(const bf16x8*)&Xs[(16 + l15)*XS_STRIDE + ko];
            #pragma unroll
            for (int it = 0; it < 4; it++) {
                const int n = (wave + 4*it)*16 + l15;
                bf16x8 br = *(const bf16x8*)&Wihb[n*256 + ko];
                bf16x8 bz = *(const bf16x8*)&Wihb[(n + 240)*256 + ko];
                bf16x8 bn = *(const bf16x8*)&Wihb[(n + 480)*256 + ko];
                accR[it][0] = MFMA16(a0, br, accR[it][0]);
                accR[it][1] = MFMA16(a1, br, accR[it][1]);
                accZ[it][0] = MFMA16(a0, bz, accZ[it][0]);
                accZ[it][1] = MFMA16(a1, bz, accZ[it][1]);
                accN[it][0] = MFMA16(a0, bn, accN[it][0]);
                accN[it][1] = MFMA16(a1, bn, accN[it][1]);
            }
        }
        // GRU nonlinearity -> Hs (bf16)
        #pragma unroll
        for (int it = 0; it < 4; it++) {
            const int t = wave + 4*it;
            if (t < 15) {
                const int h = t*16 + l15;
                const float add_r = ghb[h],       add_z = ghb[240 + h];
                const float add_n = ghb[480 + h], mul_n = ghb[720 + h];
                const float hi = h_init[h];
                #pragma unroll
                for (int m = 0; m < 2; m++)
                    #pragma unroll
                    for (int r = 0; r < 4; r++) {
                        const int row = (m << 4) + (quad << 2) + r;
                        float rg = fast_sigmoid(accR[it][m][r] + add_r);
                        float zg = fast_sigmoid(accZ[it][m][r] + add_z);
                        float ng = fast_tanh(accN[it][m][r] + add_n + rg*mul_n);
                        Hs[row*XS_STRIDE + h] = cvt_bf16((1.0f - zg)*ng + zg*hi);
                    }
            }
        }
    }
    __syncthreads();

    // ---- GEMM2: o1 = relu(H @ W_out1^T + b) * mask2 (from register bits) ----
    {
        f32x4 acc2[8][2];
        #pragma unroll
        for (int it = 0; it < 8; it++) { acc2[it][0] = zero4; acc2[it][1] = zero4; }

        #pragma unroll
        for (int ks = 0; ks < 8; ks++) {
            const int ko = ks*32 + quad*8;
            bf16x8 a0 = *(const bf16x8*)&Hs[l15*XS_STRIDE + ko];
            bf16x8 a1 = *(const bf16x8*)&Hs[(16 + l15)*XS_STRIDE + ko];
            #pragma unroll
            for (int it = 0; it < 8; it++) {
                const int n = (wave*8 + it)*16 + l15;
                bf16x8 b = *(const bf16x8*)&Wo1b[n*256 + ko];
                acc2[it][0] = MFMA16(a0, b, acc2[it][0]);
                acc2[it][1] = MFMA16(a1, b, acc2[it][1]);
            }
        }
        const float inv35 = 1.0f/0.35f;
        #pragma unroll
        for (int it = 0; it < 8; it++) {
            const int n = (wave*8 + it)*16 + l15;
            const float bb = b_out1[n];
            #pragma unroll
            for (int m = 0; m < 2; m++)
                #pragma unroll
                for (int r = 0; r < 4; r++) {
                    const int row = (m << 4) + (quad << 2) + r;
                    float o = fmaxf(acc2[it][m][r] + bb, 0.0f) * inv35;
                    o = ((m2 >> (it*8 + m*4 + r)) & 1) ? o : 0.0f;
                    O1s[row*O1_STRIDE + n] = cvt_bf16(o);
                }
        }
    }
    __syncthreads();

    // ---- GEMM3: K = o1 @ W_out2^T + b; corr = K.inno; ensemble write ----
    {
        f32x4 acc3[2][2];
        #pragma unroll
        for (int it = 0; it < 2; it++) {
            const int n = (wave*2 + it)*16 + l15;
            const float bo = b_out2[n];
            f32x4 v = {bo, bo, bo, bo};
            acc3[it][0] = v; acc3[it][1] = v;
        }
        #pragma unroll
        for (int ks = 0; ks < 16; ks++) {
            const int ko = ks*32 + quad*8;
            bf16x8 a0 = *(const bf16x8*)&O1s[l15*O1_STRIDE + ko];
            bf16x8 a1 = *(const bf16x8*)&O1s[(16 + l15)*O1_STRIDE + ko];
            #pragma unroll
            for (int it = 0; it < 2; it++) {
                const int n = (wave*2 + it)*16 + l15;
                bf16x8 b = *(const bf16x8*)&Wo2b[n*512 + ko];
                acc3[it][0] = MFMA16(a0, b, acc3[it][0]);
                acc3[it][1] = MFMA16(a1, b, acc3[it][1]);
            }
        }
        #pragma unroll
        for (int it = 0; it < 2; it++) {
            const int n = (wave*2 + it)*16 + l15;
            const int s = n >> 3, o = n & 7;
            #pragma unroll
            for (int m = 0; m < 2; m++)
                #pragma unroll
                for (int r = 0; r < 4; r++) {
                    const int row = (m << 4) + (quad << 2) + r;
                    float v = acc3[it][m][r] * InnoS[row*8 + o];
                    v += __shfl_xor(v, 1);
                    v += __shfl_xor(v, 2);
                    v += __shfl_xor(v, 4);
                    if (o == 0)
                        ens[((size_t)(b0 + row)*J_DIM + j)*16 + s] = XPs[row*16 + s] + v;
                }
        }
    }
}

// ---------------------------------------------------------------------------
// final: mean/var(ddof=1) over J per (b,s) + reg scalar
// ---------------------------------------------------------------------------
__global__ void k_final(const float* __restrict__ ens, float* __restrict__ out)
{
    int t = blockIdx.x * 256 + threadIdx.x;   // 65536 = B*S
    int b = t >> 4, s = t & 15;
    float v[32];
    #pragma unroll
    for (int jj = 0; jj < 32; jj++) v[jj] = ens[((size_t)b*32 + jj)*16 + s];
    float m = 0.f;
    #pragma unroll
    for (int jj = 0; jj < 32; jj++) m += v[jj];
    m *= (1.0f/32.0f);
    float var = 0.f;
    #pragma unroll
    for (int jj = 0; jj < 32; jj++) { float d = v[jj] - m; var = fmaf(d, d, var); }
    var *= (1.0f/31.0f);
    out[OUT_X + t] = m;
    out[OUT_P + t] = var;
    if (t == 0) out[OUT_REG] = 1.3405938195945778f;  // ln2 + H(0.65)
}

// ---------------------------------------------------------------------------
extern "C" void kernel_launch(void* const* d_in, const int* in_sizes, int n_in,
                              void* d_out, int out_size, void* d_ws, size_t ws_size,
                              hipStream_t stream)
{
    (void)in_sizes; (void)n_in; (void)out_size; (void)ws_size;
    const float* y_t    = (const float*)d_in[0];
    const float* xprev  = (const float*)d_in[1];
    const float* F      = (const float*)d_in[2];
    const float* Hm     = (const float*)d_in[3];
    const float* Wfc    = (const float*)d_in[4];
    const float* bfc    = (const float*)d_in[5];
    const float* W_ih   = (const float*)d_in[6];
    const float* W_hh   = (const float*)d_in[7];
    const float* b_ih   = (const float*)d_in[8];
    const float* b_hh   = (const float*)d_in[9];
    const float* W_o1   = (const float*)d_in[10];
    const float* b_o1   = (const float*)d_in[11];
    const float* W_o2   = (const float*)d_in[12];
    const float* b_o2   = (const float*)d_in[13];
    const float* h_init = (const float*)d_in[14];
    const float* u1     = (const float*)d_in[15];
    const float* u2     = (const float*)d_in[16];

    float* out = (float*)d_out;
    float* ws  = (float*)d_ws;
    float* x_pred = ws + WS_XPRED;
    float* inno   = ws + WS_INNO;
    float* x_in0  = ws + WS_XIN0;
    float* ghb    = ws + WS_GH;
    unsigned short* Wihb = (unsigned short*)((char*)d_ws + WS_WB_OFF);
    unsigned short* Wo1b = Wihb + 768*256;
    unsigned short* Wo2b = Wo1b + 512*256;
    float* ens    = out + OUT_ENS;

    k_aux<<<dim3(1536), dim3(256), 0, stream>>>(W_ih, W_hh, b_ih, b_hh, h_init,
                                                W_o1, W_o2, Wihb, Wo1b, Wo2b, ghb);
    k_pre<<<dim3(16, 16), dim3(256), 0, stream>>>(y_t, xprev, F, Hm, Wfc, bfc,
                                                  x_pred, inno, x_in0);
    k_main<<<dim3(4096), dim3(256), 0, stream>>>(x_in0, u1, u2, Wihb, ghb, h_init,
                                                 Wo1b, b_o1, Wo2b, b_o2,
                                                 x_pred, inno, ens);
    k_final<<<dim3(256), dim3(256), 0, stream>>>(ens, out);
}